// Round 1
// baseline (400.427 us; speedup 1.0000x reference)
//
#include <hip/hip_runtime.h>
#include <hip/hip_bf16.h>

// Problem constants
constexpr int Bsz = 2048;   // batch
constexpr int Iin = 6156;   // input features (= K = N of the big GEMM)
constexpr int IF  = 6159;   // I + O (fin_w row length)
constexpr int Kp  = 6208;   // K padded to multiple of 64 (97 * 64)
constexpr int Np  = 6272;   // N padded to multiple of 128 (49 * 128)

typedef __attribute__((ext_vector_type(8))) short short8;
typedef __attribute__((ext_vector_type(4))) float f32x4;

__device__ __forceinline__ short f2bf(float f) {
    union { float f; unsigned u; } v; v.f = f;
    unsigned r = v.u + 0x7FFFu + ((v.u >> 16) & 1u);   // RNE
    return (short)(r >> 16);
}

__device__ __forceinline__ short8 pack8(float4 a, float4 b) {
    short8 r;
    r[0] = f2bf(a.x); r[1] = f2bf(a.y); r[2] = f2bf(a.z); r[3] = f2bf(a.w);
    r[4] = f2bf(b.x); r[5] = f2bf(b.y); r[6] = f2bf(b.z); r[7] = f2bf(b.w);
    return r;
}

// ---------------------------------------------------------------------------
// Kernel 1: linear path + bias; fully initializes d_out.
// out[b,o] = fin_b[o] + sum_k fin_w[o,k] * (lin_b[k] + sum_j x[b,j]*lin_w[k,j])
// ---------------------------------------------------------------------------
__global__ void linear_init_kernel(const float* __restrict__ x,
                                   const float* __restrict__ lin_w,
                                   const float* __restrict__ lin_b,
                                   const float* __restrict__ fin_w,
                                   const float* __restrict__ fin_b,
                                   float* __restrict__ out) {
    int wid  = threadIdx.x >> 6;
    int lane = threadIdx.x & 63;
    int b = blockIdx.x * 4 + wid;
    if (b >= Bsz) return;
    const float4* xr = (const float4*)(x + (size_t)b * Iin);
    const float4* w0 = (const float4*)(lin_w);
    const float4* w1 = (const float4*)(lin_w + Iin);
    const float4* w2 = (const float4*)(lin_w + 2 * Iin);
    float s0 = 0.f, s1 = 0.f, s2 = 0.f;
    for (int i = lane; i < Iin / 4; i += 64) {   // 1539 float4s
        float4 xv = xr[i];
        float4 a0 = w0[i], a1 = w1[i], a2 = w2[i];
        s0 += xv.x * a0.x + xv.y * a0.y + xv.z * a0.z + xv.w * a0.w;
        s1 += xv.x * a1.x + xv.y * a1.y + xv.z * a1.z + xv.w * a1.w;
        s2 += xv.x * a2.x + xv.y * a2.y + xv.z * a2.z + xv.w * a2.w;
    }
    #pragma unroll
    for (int off = 1; off < 64; off <<= 1) {
        s0 += __shfl_xor(s0, off, 64);
        s1 += __shfl_xor(s1, off, 64);
        s2 += __shfl_xor(s2, off, 64);
    }
    if (lane == 0) {
        float l0 = s0 + lin_b[0], l1 = s1 + lin_b[1], l2 = s2 + lin_b[2];
        #pragma unroll
        for (int o = 0; o < 3; ++o) {
            out[b * 3 + o] = fin_b[o]
                + fin_w[(size_t)o * IF + 0] * l0
                + fin_w[(size_t)o * IF + 1] * l1
                + fin_w[(size_t)o * IF + 2] * l2;
        }
    }
}

// ---------------------------------------------------------------------------
// Kernel 2: f32 -> bf16 conversion with zero padding.
// dst is [rows][Kp]; src is [src_rows][Iin].
// ---------------------------------------------------------------------------
__global__ void convert_kernel(const float* __restrict__ src,
                               short* __restrict__ dst,
                               int rows, int src_rows) {
    const int segs = Kp / 8;   // 776
    int total = rows * segs;
    for (int c = blockIdx.x * blockDim.x + threadIdx.x; c < total;
         c += gridDim.x * blockDim.x) {
        int r   = c / segs;
        int col = (c - r * segs) * 8;
        short8 st;
        if (r < src_rows && col + 8 <= Iin) {
            const float* s = src + (size_t)r * Iin + col;
            float4 f0 = *(const float4*)s;
            float4 f1 = *(const float4*)(s + 4);
            st = pack8(f0, f1);
        } else if (r < src_rows && col < Iin) {
            const float* s = src + (size_t)r * Iin + col;
            #pragma unroll
            for (int e = 0; e < 8; ++e) {
                float v = (col + e < Iin) ? s[e] : 0.f;
                st[e] = f2bf(v);
            }
        } else {
            #pragma unroll
            for (int e = 0; e < 8; ++e) st[e] = 0;
        }
        *(short8*)&dst[(size_t)r * Kp + col] = st;
    }
}

// ---------------------------------------------------------------------------
// Kernel 3: fused GEMM z = x @ w_int^T (bf16 MFMA) + interaction epilogue.
// C-tile 128x128, BK=64, 4 waves (2x2 of 64x64). m97-style single LDS buffer.
// Epilogue: out[b,o] += sum_i fin_w[o,3+i] * x[b,i] * z[b,i] over this tile.
// PRE=true : operands pre-converted bf16 in ws (global_load_lds staging).
// PRE=false: stage f32 from the original inputs, convert in-register.
// ---------------------------------------------------------------------------
template <bool PRE>
__global__ __launch_bounds__(256) void gemm_fused(
    const short* __restrict__ xb, const short* __restrict__ wb,
    const float* __restrict__ xf, const float* __restrict__ wf,
    const float* __restrict__ finw, float* __restrict__ out) {

    __shared__ short lsA[128 * 64];
    __shared__ short lsB[128 * 64];
    __shared__ float part[128][3];

    int tid  = threadIdx.x;
    int lane = tid & 63;
    int wid  = tid >> 6;
    int wm   = wid & 1;        // wave row (0..1)
    int wn   = wid >> 1;       // wave col (0..1)

    int tile = blockIdx.x;     // 16 * 49 tiles; tm is the fast index (L2 reuse of w-tile)
    int tm = tile & 15;
    int tn = tile >> 4;
    int bm0 = tm << 7;
    int in0 = tn << 7;

    f32x4 acc[4][4];
    #pragma unroll
    for (int m = 0; m < 4; ++m)
        #pragma unroll
        for (int n = 0; n < 4; ++n)
            acc[m][n] = (f32x4){0.f, 0.f, 0.f, 0.f};

    for (int k0 = 0; k0 < Kp; k0 += 64) {
        if constexpr (PRE) {
            const short* Ab = xb + (size_t)bm0 * Kp + k0;
            const short* Bb = wb + (size_t)in0 * Kp + k0;
            int r   = (lane >> 3);       // 0..7 within the 8-row slab
            int seg = lane & 7;          // 8-bf16 segment
            #pragma unroll
            for (int it = 0; it < 4; ++it) {
                int rbase = wid * 32 + it * 8;
                __builtin_amdgcn_global_load_lds(
                    (const __attribute__((address_space(1))) void*)(Ab + (size_t)(rbase + r) * Kp + seg * 8),
                    (__attribute__((address_space(3))) void*)&lsA[rbase * 64], 16, 0, 0);
                __builtin_amdgcn_global_load_lds(
                    (const __attribute__((address_space(1))) void*)(Bb + (size_t)(rbase + r) * Kp + seg * 8),
                    (__attribute__((address_space(3))) void*)&lsB[rbase * 64], 16, 0, 0);
            }
        } else {
            #pragma unroll
            for (int it = 0; it < 4; ++it) {
                int idx = it * 256 + tid;
                int r   = idx >> 3;
                int seg = idx & 7;
                int kc  = k0 + seg * 8;
                {   // A tile: rows always valid (Bsz divides evenly)
                    const float* s = xf + (size_t)(bm0 + r) * Iin + kc;
                    short8 st;
                    if (kc + 8 <= Iin) {
                        float4 f0 = *(const float4*)s;
                        float4 f1 = *(const float4*)(s + 4);
                        st = pack8(f0, f1);
                    } else {
                        #pragma unroll
                        for (int e = 0; e < 8; ++e) {
                            float v = (kc + e < Iin) ? s[e] : 0.f;
                            st[e] = f2bf(v);
                        }
                    }
                    *(short8*)&lsA[r * 64 + seg * 8] = st;
                }
                {   // B tile: mask rows >= Iin (N tail)
                    int grow = in0 + r;
                    short8 st;
                    if (grow < Iin && kc + 8 <= Iin) {
                        const float* s = wf + (size_t)grow * Iin + kc;
                        float4 f0 = *(const float4*)s;
                        float4 f1 = *(const float4*)(s + 4);
                        st = pack8(f0, f1);
                    } else if (grow < Iin) {
                        const float* s = wf + (size_t)grow * Iin + kc;
                        #pragma unroll
                        for (int e = 0; e < 8; ++e) {
                            float v = (kc + e < Iin) ? s[e] : 0.f;
                            st[e] = f2bf(v);
                        }
                    } else {
                        #pragma unroll
                        for (int e = 0; e < 8; ++e) st[e] = 0;
                    }
                    *(short8*)&lsB[r * 64 + seg * 8] = st;
                }
            }
        }
        __syncthreads();

        #pragma unroll
        for (int kk = 0; kk < 2; ++kk) {
            int ko = kk * 32 + ((lane >> 4) << 3);   // k-offset within tile row
            short8 af[4], bfr[4];
            #pragma unroll
            for (int m = 0; m < 4; ++m)
                af[m] = *(const short8*)&lsA[(wm * 64 + m * 16 + (lane & 15)) * 64 + ko];
            #pragma unroll
            for (int n = 0; n < 4; ++n)
                bfr[n] = *(const short8*)&lsB[(wn * 64 + n * 16 + (lane & 15)) * 64 + ko];
            #pragma unroll
            for (int m = 0; m < 4; ++m)
                #pragma unroll
                for (int n = 0; n < 4; ++n)
                    acc[m][n] = __builtin_amdgcn_mfma_f32_16x16x32_bf16(
                        af[m], bfr[n], acc[m][n], 0, 0, 0);
        }
        __syncthreads();
    }

    // ---- epilogue: contract tile against fin_w[:,3:] and x, reduce, accumulate
    for (int t = tid; t < 384; t += 256) ((float*)part)[t] = 0.f;
    __syncthreads();

    #pragma unroll
    for (int m = 0; m < 4; ++m) {
        int rowbase = bm0 + wm * 64 + m * 16 + ((lane >> 4) << 2);
        #pragma unroll
        for (int r = 0; r < 4; ++r) {
            int b = rowbase + r;
            float s0 = 0.f, s1 = 0.f, s2 = 0.f;
            #pragma unroll
            for (int n = 0; n < 4; ++n) {
                int gi = in0 + wn * 64 + n * 16 + (lane & 15);
                if (gi < Iin) {
                    float inter = acc[m][n][r] * xf[(size_t)b * Iin + gi];
                    s0 += inter * finw[(size_t)0 * IF + 3 + gi];
                    s1 += inter * finw[(size_t)1 * IF + 3 + gi];
                    s2 += inter * finw[(size_t)2 * IF + 3 + gi];
                }
            }
            #pragma unroll
            for (int off = 1; off < 16; off <<= 1) {
                s0 += __shfl_xor(s0, off, 64);
                s1 += __shfl_xor(s1, off, 64);
                s2 += __shfl_xor(s2, off, 64);
            }
            if ((lane & 15) == 0) {
                int lr = b - bm0;
                atomicAdd(&part[lr][0], s0);
                atomicAdd(&part[lr][1], s1);
                atomicAdd(&part[lr][2], s2);
            }
        }
    }
    __syncthreads();
    for (int t = tid; t < 384; t += 256) {
        int lr = t / 3, o = t - lr * 3;
        atomicAdd(&out[(size_t)(bm0 + lr) * 3 + o], part[lr][o]);
    }
}

// ---------------------------------------------------------------------------
extern "C" void kernel_launch(void* const* d_in, const int* in_sizes, int n_in,
                              void* d_out, int out_size, void* d_ws, size_t ws_size,
                              hipStream_t stream) {
    const float* x     = (const float*)d_in[0];
    const float* lin_w = (const float*)d_in[1];
    const float* lin_b = (const float*)d_in[2];
    const float* w_int = (const float*)d_in[3];
    const float* fin_w = (const float*)d_in[4];
    const float* fin_b = (const float*)d_in[5];
    float* out = (float*)d_out;

    // 1) linear path, initializes all of d_out
    linear_init_kernel<<<Bsz / 4, 256, 0, stream>>>(x, lin_w, lin_b, fin_w, fin_b, out);

    const size_t xb_elems = (size_t)Bsz * Kp;   // 12,713,984
    const size_t wb_elems = (size_t)Np * Kp;    // 38,936,576
    const size_t need = (xb_elems + wb_elems) * sizeof(short);

    const int ntiles = (Bsz / 128) * (Np / 128);   // 16 * 49 = 784

    if (ws_size >= need) {
        short* xb = (short*)d_ws;
        short* wb = xb + xb_elems;
        convert_kernel<<<2048, 256, 0, stream>>>(x, xb, Bsz, Bsz);
        convert_kernel<<<2048, 256, 0, stream>>>(w_int, wb, Np, Iin);
        gemm_fused<true><<<ntiles, 256, 0, stream>>>(xb, wb, x, w_int, fin_w, out);
    } else {
        gemm_fused<false><<<ntiles, 256, 0, stream>>>(nullptr, nullptr, x, w_int, fin_w, out);
    }
}

// Round 2
// 349.719 us; speedup vs baseline: 1.1450x; 1.1450x over previous
//
#include <hip/hip_runtime.h>
#include <hip/hip_bf16.h>

// Problem constants
constexpr int Bsz = 2048;   // batch
constexpr int Iin = 6156;   // input features (= K = N of the big GEMM)
constexpr int IF  = 6159;   // I + O (fin_w row length)
constexpr int Kp  = 6208;   // K padded to multiple of 64 (97 * 64)
constexpr int Np  = 6272;   // N padded to multiple of 128 (49 * 128)

typedef __attribute__((ext_vector_type(8))) short short8;
typedef __attribute__((ext_vector_type(4))) float f32x4;

__device__ __forceinline__ short f2bf(float f) {
    union { float f; unsigned u; } v; v.f = f;
    unsigned r = v.u + 0x7FFFu + ((v.u >> 16) & 1u);   // RNE
    return (short)(r >> 16);
}

__device__ __forceinline__ short8 pack8(float4 a, float4 b) {
    short8 r;
    r[0] = f2bf(a.x); r[1] = f2bf(a.y); r[2] = f2bf(a.z); r[3] = f2bf(a.w);
    r[4] = f2bf(b.x); r[5] = f2bf(b.y); r[6] = f2bf(b.z); r[7] = f2bf(b.w);
    return r;
}

// ---------------------------------------------------------------------------
// Kernel 1: linear path + bias; fully initializes d_out.
// ---------------------------------------------------------------------------
__global__ void linear_init_kernel(const float* __restrict__ x,
                                   const float* __restrict__ lin_w,
                                   const float* __restrict__ lin_b,
                                   const float* __restrict__ fin_w,
                                   const float* __restrict__ fin_b,
                                   float* __restrict__ out) {
    int wid  = threadIdx.x >> 6;
    int lane = threadIdx.x & 63;
    int b = blockIdx.x * 4 + wid;
    if (b >= Bsz) return;
    const float4* xr = (const float4*)(x + (size_t)b * Iin);
    const float4* w0 = (const float4*)(lin_w);
    const float4* w1 = (const float4*)(lin_w + Iin);
    const float4* w2 = (const float4*)(lin_w + 2 * Iin);
    float s0 = 0.f, s1 = 0.f, s2 = 0.f;
    for (int i = lane; i < Iin / 4; i += 64) {
        float4 xv = xr[i];
        float4 a0 = w0[i], a1 = w1[i], a2 = w2[i];
        s0 += xv.x * a0.x + xv.y * a0.y + xv.z * a0.z + xv.w * a0.w;
        s1 += xv.x * a1.x + xv.y * a1.y + xv.z * a1.z + xv.w * a1.w;
        s2 += xv.x * a2.x + xv.y * a2.y + xv.z * a2.z + xv.w * a2.w;
    }
    #pragma unroll
    for (int off = 1; off < 64; off <<= 1) {
        s0 += __shfl_xor(s0, off, 64);
        s1 += __shfl_xor(s1, off, 64);
        s2 += __shfl_xor(s2, off, 64);
    }
    if (lane == 0) {
        float l0 = s0 + lin_b[0], l1 = s1 + lin_b[1], l2 = s2 + lin_b[2];
        #pragma unroll
        for (int o = 0; o < 3; ++o) {
            out[b * 3 + o] = fin_b[o]
                + fin_w[(size_t)o * IF + 0] * l0
                + fin_w[(size_t)o * IF + 1] * l1
                + fin_w[(size_t)o * IF + 2] * l2;
        }
    }
}

// ---------------------------------------------------------------------------
// Kernel 2: f32 -> bf16 conversion, zero padding, PLUS segment XOR swizzle.
// dst[(r, blk*8 + sub)] holds source columns blk*64 + (sub^(r&7))*8 .. +8.
// The GEMM stages this linearly into LDS and un-XORs at ds_read time
// (rule #21: linear LDS dest + pre-swizzled source + swizzled read).
// ---------------------------------------------------------------------------
__global__ void convert_kernel(const float* __restrict__ src,
                               short* __restrict__ dst,
                               int rows, int src_rows) {
    const int segs = Kp / 8;   // 776
    int total = rows * segs;
    for (int c = blockIdx.x * blockDim.x + threadIdx.x; c < total;
         c += gridDim.x * blockDim.x) {
        int r     = c / segs;
        int s_dst = c - r * segs;
        int blk   = s_dst >> 3;
        int sub_d = s_dst & 7;
        int src_col = (blk << 6) + ((sub_d ^ (r & 7)) << 3);  // source column base
        short8 st;
        if (r < src_rows && src_col + 8 <= Iin) {
            const float* s = src + (size_t)r * Iin + src_col;
            float4 f0 = *(const float4*)s;
            float4 f1 = *(const float4*)(s + 4);
            st = pack8(f0, f1);
        } else if (r < src_rows && src_col < Iin) {
            const float* s = src + (size_t)r * Iin + src_col;
            #pragma unroll
            for (int e = 0; e < 8; ++e) {
                float v = (src_col + e < Iin) ? s[e] : 0.f;
                st[e] = f2bf(v);
            }
        } else {
            #pragma unroll
            for (int e = 0; e < 8; ++e) st[e] = 0;
        }
        *(short8*)&dst[(size_t)r * Kp + (size_t)s_dst * 8] = st;
    }
}

// ---------------------------------------------------------------------------
// Kernel 3: fused GEMM z = x @ w_int^T (bf16 MFMA) + interaction epilogue.
// C-tile 128x128, BK=64, 4 waves (2x2 of 64x64). LDS tiles hold the
// segment-XOR-swizzled layout; ds_read applies  sub' = sub ^ (row&7).
// ---------------------------------------------------------------------------
template <bool PRE>
__global__ __launch_bounds__(256) void gemm_fused(
    const short* __restrict__ xb, const short* __restrict__ wb,
    const float* __restrict__ xf, const float* __restrict__ wf,
    const float* __restrict__ finw, float* __restrict__ out) {

    __shared__ short lsA[128 * 64];
    __shared__ short lsB[128 * 64];
    __shared__ float part[128][3];

    int tid  = threadIdx.x;
    int lane = tid & 63;
    int wid  = tid >> 6;
    int wm   = wid & 1;        // wave row (0..1)
    int wn   = wid >> 1;       // wave col (0..1)

    // Bijective XCD-chunk swizzle: 784 tiles, 8 XCDs, 98 tiles per XCD chunk.
    int ntiles = (Bsz / 128) * (Np / 128);        // 784
    int tile = (blockIdx.x & 7) * (ntiles >> 3) + (blockIdx.x >> 3);
    int tm = tile & 15;        // fast index: 16 consecutive tiles share B-tile
    int tn = tile >> 4;
    int bm0 = tm << 7;
    int in0 = tn << 7;

    f32x4 acc[4][4];
    #pragma unroll
    for (int m = 0; m < 4; ++m)
        #pragma unroll
        for (int n = 0; n < 4; ++n)
            acc[m][n] = (f32x4){0.f, 0.f, 0.f, 0.f};

    for (int k0 = 0; k0 < Kp; k0 += 64) {
        if constexpr (PRE) {
            const short* Ab = xb + (size_t)bm0 * Kp + k0;
            const short* Bb = wb + (size_t)in0 * Kp + k0;
            int r   = (lane >> 3);       // 0..7 within the 8-row slab
            int seg = lane & 7;          // 8-bf16 segment (already swizzled in ws)
            #pragma unroll
            for (int it = 0; it < 4; ++it) {
                int rbase = wid * 32 + it * 8;
                __builtin_amdgcn_global_load_lds(
                    (const __attribute__((address_space(1))) void*)(Ab + (size_t)(rbase + r) * Kp + seg * 8),
                    (__attribute__((address_space(3))) void*)&lsA[rbase * 64], 16, 0, 0);
                __builtin_amdgcn_global_load_lds(
                    (const __attribute__((address_space(1))) void*)(Bb + (size_t)(rbase + r) * Kp + seg * 8),
                    (__attribute__((address_space(3))) void*)&lsB[rbase * 64], 16, 0, 0);
            }
        } else {
            // reg-staged: apply the XOR swizzle at ds_write time
            #pragma unroll
            for (int it = 0; it < 4; ++it) {
                int idx = it * 256 + tid;
                int r   = idx >> 3;
                int seg = idx & 7;
                int kc  = k0 + seg * 8;                 // source column
                int sd  = (seg ^ (r & 7)) << 3;         // swizzled LDS slot
                {   // A tile
                    const float* s = xf + (size_t)(bm0 + r) * Iin + kc;
                    short8 st;
                    if (kc + 8 <= Iin) {
                        float4 f0 = *(const float4*)s;
                        float4 f1 = *(const float4*)(s + 4);
                        st = pack8(f0, f1);
                    } else {
                        #pragma unroll
                        for (int e = 0; e < 8; ++e) {
                            float v = (kc + e < Iin) ? s[e] : 0.f;
                            st[e] = f2bf(v);
                        }
                    }
                    *(short8*)&lsA[r * 64 + sd] = st;
                }
                {   // B tile
                    int grow = in0 + r;
                    short8 st;
                    if (grow < Iin && kc + 8 <= Iin) {
                        const float* s = wf + (size_t)grow * Iin + kc;
                        float4 f0 = *(const float4*)s;
                        float4 f1 = *(const float4*)(s + 4);
                        st = pack8(f0, f1);
                    } else if (grow < Iin) {
                        const float* s = wf + (size_t)grow * Iin + kc;
                        #pragma unroll
                        for (int e = 0; e < 8; ++e) {
                            float v = (kc + e < Iin) ? s[e] : 0.f;
                            st[e] = f2bf(v);
                        }
                    } else {
                        #pragma unroll
                        for (int e = 0; e < 8; ++e) st[e] = 0;
                    }
                    *(short8*)&lsB[r * 64 + sd] = st;
                }
            }
        }
        __syncthreads();

        #pragma unroll
        for (int kk = 0; kk < 2; ++kk) {
            int q = (kk << 2) + (lane >> 4);            // k-segment 0..7
            short8 af[4], bfr[4];
            #pragma unroll
            for (int m = 0; m < 4; ++m) {
                int R = wm * 64 + m * 16 + (lane & 15);
                af[m] = *(const short8*)&lsA[R * 64 + ((q ^ (R & 7)) << 3)];
            }
            #pragma unroll
            for (int n = 0; n < 4; ++n) {
                int R = wn * 64 + n * 16 + (lane & 15);
                bfr[n] = *(const short8*)&lsB[R * 64 + ((q ^ (R & 7)) << 3)];
            }
            #pragma unroll
            for (int m = 0; m < 4; ++m)
                #pragma unroll
                for (int n = 0; n < 4; ++n)
                    acc[m][n] = __builtin_amdgcn_mfma_f32_16x16x32_bf16(
                        af[m], bfr[n], acc[m][n], 0, 0, 0);
        }
        __syncthreads();
    }

    // ---- epilogue: contract tile against fin_w[:,3:] and x, reduce, accumulate
    for (int t = tid; t < 384; t += 256) ((float*)part)[t] = 0.f;
    __syncthreads();

    #pragma unroll
    for (int m = 0; m < 4; ++m) {
        int rowbase = bm0 + wm * 64 + m * 16 + ((lane >> 4) << 2);
        #pragma unroll
        for (int r = 0; r < 4; ++r) {
            int b = rowbase + r;
            float s0 = 0.f, s1 = 0.f, s2 = 0.f;
            #pragma unroll
            for (int n = 0; n < 4; ++n) {
                int gi = in0 + wn * 64 + n * 16 + (lane & 15);
                if (gi < Iin) {
                    float inter = acc[m][n][r] * xf[(size_t)b * Iin + gi];
                    s0 += inter * finw[(size_t)0 * IF + 3 + gi];
                    s1 += inter * finw[(size_t)1 * IF + 3 + gi];
                    s2 += inter * finw[(size_t)2 * IF + 3 + gi];
                }
            }
            #pragma unroll
            for (int off = 1; off < 16; off <<= 1) {
                s0 += __shfl_xor(s0, off, 64);
                s1 += __shfl_xor(s1, off, 64);
                s2 += __shfl_xor(s2, off, 64);
            }
            if ((lane & 15) == 0) {
                int lr = b - bm0;
                atomicAdd(&part[lr][0], s0);
                atomicAdd(&part[lr][1], s1);
                atomicAdd(&part[lr][2], s2);
            }
        }
    }
    __syncthreads();
    for (int t = tid; t < 384; t += 256) {
        int lr = t / 3, o = t - lr * 3;
        atomicAdd(&out[(size_t)(bm0 + lr) * 3 + o], part[lr][o]);
    }
}

// ---------------------------------------------------------------------------
extern "C" void kernel_launch(void* const* d_in, const int* in_sizes, int n_in,
                              void* d_out, int out_size, void* d_ws, size_t ws_size,
                              hipStream_t stream) {
    const float* x     = (const float*)d_in[0];
    const float* lin_w = (const float*)d_in[1];
    const float* lin_b = (const float*)d_in[2];
    const float* w_int = (const float*)d_in[3];
    const float* fin_w = (const float*)d_in[4];
    const float* fin_b = (const float*)d_in[5];
    float* out = (float*)d_out;

    // 1) linear path, initializes all of d_out
    linear_init_kernel<<<Bsz / 4, 256, 0, stream>>>(x, lin_w, lin_b, fin_w, fin_b, out);

    const size_t xb_elems = (size_t)Bsz * Kp;   // 12,713,984
    const size_t wb_elems = (size_t)Np * Kp;    // 38,936,576
    const size_t need = (xb_elems + wb_elems) * sizeof(short);

    const int ntiles = (Bsz / 128) * (Np / 128);   // 16 * 49 = 784

    if (ws_size >= need) {
        short* xb = (short*)d_ws;
        short* wb = xb + xb_elems;
        convert_kernel<<<2048, 256, 0, stream>>>(x, xb, Bsz, Bsz);
        convert_kernel<<<2048, 256, 0, stream>>>(w_int, wb, Np, Iin);
        gemm_fused<true><<<ntiles, 256, 0, stream>>>(xb, wb, x, w_int, fin_w, out);
    } else {
        gemm_fused<false><<<ntiles, 256, 0, stream>>>(nullptr, nullptr, x, w_int, fin_w, out);
    }
}

// Round 3
// 289.334 us; speedup vs baseline: 1.3840x; 1.2087x over previous
//
#include <hip/hip_runtime.h>
#include <hip/hip_bf16.h>

// Problem constants
constexpr int Bsz = 2048;   // batch
constexpr int Iin = 6156;   // input features (= K = N of the big GEMM)
constexpr int IF  = 6159;   // I + O (fin_w row length)
constexpr int Kp  = 6208;   // K padded to multiple of 64 (97 * 64)
constexpr int Np  = 6272;   // N padded to multiple of 128 (49 * 128)

typedef __attribute__((ext_vector_type(8))) short short8;
typedef __attribute__((ext_vector_type(4))) float f32x4;

__device__ __forceinline__ short f2bf(float f) {
    union { float f; unsigned u; } v; v.f = f;
    unsigned r = v.u + 0x7FFFu + ((v.u >> 16) & 1u);   // RNE
    return (short)(r >> 16);
}

__device__ __forceinline__ short8 pack8(float4 a, float4 b) {
    short8 r;
    r[0] = f2bf(a.x); r[1] = f2bf(a.y); r[2] = f2bf(a.z); r[3] = f2bf(a.w);
    r[4] = f2bf(b.x); r[5] = f2bf(b.y); r[6] = f2bf(b.z); r[7] = f2bf(b.w);
    return r;
}

// ---------------------------------------------------------------------------
// Kernel 1: linear path + bias; fully initializes d_out.
// ---------------------------------------------------------------------------
__global__ void linear_init_kernel(const float* __restrict__ x,
                                   const float* __restrict__ lin_w,
                                   const float* __restrict__ lin_b,
                                   const float* __restrict__ fin_w,
                                   const float* __restrict__ fin_b,
                                   float* __restrict__ out) {
    int wid  = threadIdx.x >> 6;
    int lane = threadIdx.x & 63;
    int b = blockIdx.x * 4 + wid;
    if (b >= Bsz) return;
    const float4* xr = (const float4*)(x + (size_t)b * Iin);
    const float4* w0 = (const float4*)(lin_w);
    const float4* w1 = (const float4*)(lin_w + Iin);
    const float4* w2 = (const float4*)(lin_w + 2 * Iin);
    float s0 = 0.f, s1 = 0.f, s2 = 0.f;
    for (int i = lane; i < Iin / 4; i += 64) {
        float4 xv = xr[i];
        float4 a0 = w0[i], a1 = w1[i], a2 = w2[i];
        s0 += xv.x * a0.x + xv.y * a0.y + xv.z * a0.z + xv.w * a0.w;
        s1 += xv.x * a1.x + xv.y * a1.y + xv.z * a1.z + xv.w * a1.w;
        s2 += xv.x * a2.x + xv.y * a2.y + xv.z * a2.z + xv.w * a2.w;
    }
    #pragma unroll
    for (int off = 1; off < 64; off <<= 1) {
        s0 += __shfl_xor(s0, off, 64);
        s1 += __shfl_xor(s1, off, 64);
        s2 += __shfl_xor(s2, off, 64);
    }
    if (lane == 0) {
        float l0 = s0 + lin_b[0], l1 = s1 + lin_b[1], l2 = s2 + lin_b[2];
        #pragma unroll
        for (int o = 0; o < 3; ++o) {
            out[b * 3 + o] = fin_b[o]
                + fin_w[(size_t)o * IF + 0] * l0
                + fin_w[(size_t)o * IF + 1] * l1
                + fin_w[(size_t)o * IF + 2] * l2;
        }
    }
}

// ---------------------------------------------------------------------------
// Kernel 2: f32 -> bf16 conversion, zero padding, PLUS segment XOR swizzle.
// dst[(r, blk*8 + sub)] holds source columns blk*64 + (sub^(r&7))*8 .. +8.
// ---------------------------------------------------------------------------
__global__ void convert_kernel(const float* __restrict__ src,
                               short* __restrict__ dst,
                               int rows, int src_rows) {
    const int segs = Kp / 8;   // 776
    int total = rows * segs;
    for (int c = blockIdx.x * blockDim.x + threadIdx.x; c < total;
         c += gridDim.x * blockDim.x) {
        int r     = c / segs;
        int s_dst = c - r * segs;
        int blk   = s_dst >> 3;
        int sub_d = s_dst & 7;
        int src_col = (blk << 6) + ((sub_d ^ (r & 7)) << 3);
        short8 st;
        if (r < src_rows && src_col + 8 <= Iin) {
            const float* s = src + (size_t)r * Iin + src_col;
            float4 f0 = *(const float4*)s;
            float4 f1 = *(const float4*)(s + 4);
            st = pack8(f0, f1);
        } else if (r < src_rows && src_col < Iin) {
            const float* s = src + (size_t)r * Iin + src_col;
            #pragma unroll
            for (int e = 0; e < 8; ++e) {
                float v = (src_col + e < Iin) ? s[e] : 0.f;
                st[e] = f2bf(v);
            }
        } else {
            #pragma unroll
            for (int e = 0; e < 8; ++e) st[e] = 0;
        }
        *(short8*)&dst[(size_t)r * Kp + (size_t)s_dst * 8] = st;
    }
}

// ---------------------------------------------------------------------------
// Stage one 128x64 bf16 tile pair (A,B) into LDS via global_load_lds.
// 8 loads per thread (4 A + 4 B), LDS dest = wave-uniform base + lane*16.
// ---------------------------------------------------------------------------
__device__ __forceinline__ void stage_tile(const short* __restrict__ Ab,
                                           const short* __restrict__ Bb,
                                           short* la, short* lb,
                                           int lane, int wid) {
    int r   = lane >> 3;
    int seg = (lane & 7) << 3;
    #pragma unroll
    for (int it = 0; it < 4; ++it) {
        int rbase = wid * 32 + it * 8;
        __builtin_amdgcn_global_load_lds(
            (const __attribute__((address_space(1))) void*)(Ab + (size_t)(rbase + r) * Kp + seg),
            (__attribute__((address_space(3))) void*)(la + rbase * 64), 16, 0, 0);
        __builtin_amdgcn_global_load_lds(
            (const __attribute__((address_space(1))) void*)(Bb + (size_t)(rbase + r) * Kp + seg),
            (__attribute__((address_space(3))) void*)(lb + rbase * 64), 16, 0, 0);
    }
}

// ---------------------------------------------------------------------------
// Kernel 3 (PRE path): pipelined GEMM z = x @ w_int^T + interaction epilogue.
// 128x128 C-tile, BK=64, 4 waves. Double-buffered LDS, counted vmcnt(8),
// raw s_barrier (no compiler vmcnt(0) drain). Stage for kt+2 is issued after
// barrier-A (all reads of that buffer done) and overlaps this tile's MFMA.
// ---------------------------------------------------------------------------
__global__ __launch_bounds__(256) void gemm_pipe(
    const short* __restrict__ xb, const short* __restrict__ wb,
    const float* __restrict__ xf, const float* __restrict__ finw,
    float* __restrict__ out) {

    __shared__ short lsA[2][128 * 64];
    __shared__ short lsB[2][128 * 64];
    __shared__ float part[128][3];

    int tid  = threadIdx.x;
    int lane = tid & 63;
    int wid  = tid >> 6;
    int wm   = wid & 1;
    int wn   = wid >> 1;

    int ntiles = (Bsz / 128) * (Np / 128);        // 784
    int tile = (blockIdx.x & 7) * (ntiles >> 3) + (blockIdx.x >> 3);
    int tm = tile & 15;
    int tn = tile >> 4;
    int bm0 = tm << 7;
    int in0 = tn << 7;

    const short* Abase = xb + (size_t)bm0 * Kp;
    const short* Bbase = wb + (size_t)in0 * Kp;

    f32x4 acc[4][4];
    #pragma unroll
    for (int m = 0; m < 4; ++m)
        #pragma unroll
        for (int n = 0; n < 4; ++n)
            acc[m][n] = (f32x4){0.f, 0.f, 0.f, 0.f};

    constexpr int NT = Kp / 64;                   // 97

    // prologue: stage tiles 0 and 1, wait for tile 0 (8 newest may float)
    stage_tile(Abase, Bbase, lsA[0], lsB[0], lane, wid);
    stage_tile(Abase + 64, Bbase + 64, lsA[1], lsB[1], lane, wid);
    asm volatile("s_waitcnt vmcnt(8)" ::: "memory");
    __builtin_amdgcn_s_barrier();

    int rAb = wm * 64 + (lane & 15);
    int rBb = wn * 64 + (lane & 15);
    int qk  = lane >> 4;

    for (int kt = 0; kt < NT; ++kt) {
        const short* la = lsA[kt & 1];
        const short* lb = lsB[kt & 1];

        short8 af[4][2], bfr[4][2];
        #pragma unroll
        for (int m = 0; m < 4; ++m) {
            int R = rAb + m * 16;
            #pragma unroll
            for (int kk = 0; kk < 2; ++kk) {
                int q = qk + kk * 4;
                af[m][kk] = *(const short8*)&la[R * 64 + ((q ^ (R & 7)) << 3)];
            }
        }
        #pragma unroll
        for (int n = 0; n < 4; ++n) {
            int R = rBb + n * 16;
            #pragma unroll
            for (int kk = 0; kk < 2; ++kk) {
                int q = qk + kk * 4;
                bfr[n][kk] = *(const short8*)&lb[R * 64 + ((q ^ (R & 7)) << 3)];
            }
        }
        asm volatile("s_waitcnt lgkmcnt(0)" ::: "memory");
        __builtin_amdgcn_sched_barrier(0);
        __builtin_amdgcn_s_barrier();             // A: all waves' reads done
        __builtin_amdgcn_sched_barrier(0);

        if (kt + 2 < NT) {
            stage_tile(Abase + (size_t)(kt + 2) * 64, Bbase + (size_t)(kt + 2) * 64,
                       lsA[kt & 1], lsB[kt & 1], lane, wid);
        }
        __builtin_amdgcn_sched_barrier(0);

        #pragma unroll
        for (int kk = 0; kk < 2; ++kk)
            #pragma unroll
            for (int m = 0; m < 4; ++m)
                #pragma unroll
                for (int n = 0; n < 4; ++n)
                    acc[m][n] = __builtin_amdgcn_mfma_f32_16x16x32_bf16(
                        af[m][kk], bfr[n][kk], acc[m][n], 0, 0, 0);
        __builtin_amdgcn_sched_barrier(0);

        if (kt < NT - 2)
            asm volatile("s_waitcnt vmcnt(8)" ::: "memory");   // kt+1 landed; kt+2 in flight
        else
            asm volatile("s_waitcnt vmcnt(0)" ::: "memory");   // tail drain
        __builtin_amdgcn_s_barrier();             // B
    }

    // ---- epilogue: contract tile against fin_w[:,3:] and x, reduce, accumulate
    for (int t = tid; t < 384; t += 256) ((float*)part)[t] = 0.f;
    __syncthreads();

    #pragma unroll
    for (int m = 0; m < 4; ++m) {
        int rowbase = bm0 + wm * 64 + m * 16 + ((lane >> 4) << 2);
        #pragma unroll
        for (int r = 0; r < 4; ++r) {
            int b = rowbase + r;
            float s0 = 0.f, s1 = 0.f, s2 = 0.f;
            #pragma unroll
            for (int n = 0; n < 4; ++n) {
                int gi = in0 + wn * 64 + n * 16 + (lane & 15);
                if (gi < Iin) {
                    float inter = acc[m][n][r] * xf[(size_t)b * Iin + gi];
                    s0 += inter * finw[(size_t)0 * IF + 3 + gi];
                    s1 += inter * finw[(size_t)1 * IF + 3 + gi];
                    s2 += inter * finw[(size_t)2 * IF + 3 + gi];
                }
            }
            #pragma unroll
            for (int off = 1; off < 16; off <<= 1) {
                s0 += __shfl_xor(s0, off, 64);
                s1 += __shfl_xor(s1, off, 64);
                s2 += __shfl_xor(s2, off, 64);
            }
            if ((lane & 15) == 0) {
                int lr = b - bm0;
                atomicAdd(&part[lr][0], s0);
                atomicAdd(&part[lr][1], s1);
                atomicAdd(&part[lr][2], s2);
            }
        }
    }
    __syncthreads();
    for (int t = tid; t < 384; t += 256) {
        int lr = t / 3, o = t - lr * 3;
        atomicAdd(&out[(size_t)(bm0 + lr) * 3 + o], part[lr][o]);
    }
}

// ---------------------------------------------------------------------------
// Fallback (no workspace): previous 2-barrier reg-staged kernel (correct, slow)
// ---------------------------------------------------------------------------
__global__ __launch_bounds__(256) void gemm_fallback(
    const float* __restrict__ xf, const float* __restrict__ wf,
    const float* __restrict__ finw, float* __restrict__ out) {

    __shared__ short lsA[128 * 64];
    __shared__ short lsB[128 * 64];
    __shared__ float part[128][3];

    int tid  = threadIdx.x;
    int lane = tid & 63;
    int wid  = tid >> 6;
    int wm   = wid & 1;
    int wn   = wid >> 1;

    int ntiles = (Bsz / 128) * (Np / 128);
    int tile = (blockIdx.x & 7) * (ntiles >> 3) + (blockIdx.x >> 3);
    int tm = tile & 15;
    int tn = tile >> 4;
    int bm0 = tm << 7;
    int in0 = tn << 7;

    f32x4 acc[4][4];
    #pragma unroll
    for (int m = 0; m < 4; ++m)
        #pragma unroll
        for (int n = 0; n < 4; ++n)
            acc[m][n] = (f32x4){0.f, 0.f, 0.f, 0.f};

    for (int k0 = 0; k0 < Kp; k0 += 64) {
        #pragma unroll
        for (int it = 0; it < 4; ++it) {
            int idx = it * 256 + tid;
            int r   = idx >> 3;
            int seg = idx & 7;
            int kc  = k0 + seg * 8;
            int sd  = (seg ^ (r & 7)) << 3;
            {
                const float* s = xf + (size_t)(bm0 + r) * Iin + kc;
                short8 st;
                if (kc + 8 <= Iin) {
                    float4 f0 = *(const float4*)s;
                    float4 f1 = *(const float4*)(s + 4);
                    st = pack8(f0, f1);
                } else {
                    #pragma unroll
                    for (int e = 0; e < 8; ++e) {
                        float v = (kc + e < Iin) ? s[e] : 0.f;
                        st[e] = f2bf(v);
                    }
                }
                *(short8*)&lsA[r * 64 + sd] = st;
            }
            {
                int grow = in0 + r;
                short8 st;
                if (grow < Iin && kc + 8 <= Iin) {
                    const float* s = wf + (size_t)grow * Iin + kc;
                    float4 f0 = *(const float4*)s;
                    float4 f1 = *(const float4*)(s + 4);
                    st = pack8(f0, f1);
                } else if (grow < Iin) {
                    const float* s = wf + (size_t)grow * Iin + kc;
                    #pragma unroll
                    for (int e = 0; e < 8; ++e) {
                        float v = (kc + e < Iin) ? s[e] : 0.f;
                        st[e] = f2bf(v);
                    }
                } else {
                    #pragma unroll
                    for (int e = 0; e < 8; ++e) st[e] = 0;
                }
                *(short8*)&lsB[r * 64 + sd] = st;
            }
        }
        __syncthreads();

        #pragma unroll
        for (int kk = 0; kk < 2; ++kk) {
            int q = (kk << 2) + (lane >> 4);
            short8 af[4], bfr[4];
            #pragma unroll
            for (int m = 0; m < 4; ++m) {
                int R = wm * 64 + m * 16 + (lane & 15);
                af[m] = *(const short8*)&lsA[R * 64 + ((q ^ (R & 7)) << 3)];
            }
            #pragma unroll
            for (int n = 0; n < 4; ++n) {
                int R = wn * 64 + n * 16 + (lane & 15);
                bfr[n] = *(const short8*)&lsB[R * 64 + ((q ^ (R & 7)) << 3)];
            }
            #pragma unroll
            for (int m = 0; m < 4; ++m)
                #pragma unroll
                for (int n = 0; n < 4; ++n)
                    acc[m][n] = __builtin_amdgcn_mfma_f32_16x16x32_bf16(
                        af[m], bfr[n], acc[m][n], 0, 0, 0);
        }
        __syncthreads();
    }

    for (int t = tid; t < 384; t += 256) ((float*)part)[t] = 0.f;
    __syncthreads();

    #pragma unroll
    for (int m = 0; m < 4; ++m) {
        int rowbase = bm0 + wm * 64 + m * 16 + ((lane >> 4) << 2);
        #pragma unroll
        for (int r = 0; r < 4; ++r) {
            int b = rowbase + r;
            float s0 = 0.f, s1 = 0.f, s2 = 0.f;
            #pragma unroll
            for (int n = 0; n < 4; ++n) {
                int gi = in0 + wn * 64 + n * 16 + (lane & 15);
                if (gi < Iin) {
                    float inter = acc[m][n][r] * xf[(size_t)b * Iin + gi];
                    s0 += inter * finw[(size_t)0 * IF + 3 + gi];
                    s1 += inter * finw[(size_t)1 * IF + 3 + gi];
                    s2 += inter * finw[(size_t)2 * IF + 3 + gi];
                }
            }
            #pragma unroll
            for (int off = 1; off < 16; off <<= 1) {
                s0 += __shfl_xor(s0, off, 64);
                s1 += __shfl_xor(s1, off, 64);
                s2 += __shfl_xor(s2, off, 64);
            }
            if ((lane & 15) == 0) {
                int lr = b - bm0;
                atomicAdd(&part[lr][0], s0);
                atomicAdd(&part[lr][1], s1);
                atomicAdd(&part[lr][2], s2);
            }
        }
    }
    __syncthreads();
    for (int t = tid; t < 384; t += 256) {
        int lr = t / 3, o = t - lr * 3;
        atomicAdd(&out[(size_t)(bm0 + lr) * 3 + o], part[lr][o]);
    }
}

// ---------------------------------------------------------------------------
extern "C" void kernel_launch(void* const* d_in, const int* in_sizes, int n_in,
                              void* d_out, int out_size, void* d_ws, size_t ws_size,
                              hipStream_t stream) {
    const float* x     = (const float*)d_in[0];
    const float* lin_w = (const float*)d_in[1];
    const float* lin_b = (const float*)d_in[2];
    const float* w_int = (const float*)d_in[3];
    const float* fin_w = (const float*)d_in[4];
    const float* fin_b = (const float*)d_in[5];
    float* out = (float*)d_out;

    linear_init_kernel<<<Bsz / 4, 256, 0, stream>>>(x, lin_w, lin_b, fin_w, fin_b, out);

    const size_t xb_elems = (size_t)Bsz * Kp;
    const size_t wb_elems = (size_t)Np * Kp;
    const size_t need = (xb_elems + wb_elems) * sizeof(short);

    const int ntiles = (Bsz / 128) * (Np / 128);   // 784

    if (ws_size >= need) {
        short* xb = (short*)d_ws;
        short* wb = xb + xb_elems;
        convert_kernel<<<2048, 256, 0, stream>>>(x, xb, Bsz, Bsz);
        convert_kernel<<<2048, 256, 0, stream>>>(w_int, wb, Np, Iin);
        gemm_pipe<<<ntiles, 256, 0, stream>>>(xb, wb, x, fin_w, out);
    } else {
        gemm_fallback<<<ntiles, 256, 0, stream>>>(x, w_int, fin_w, out);
    }
}